// Round 12
// baseline (215.917 us; speedup 1.0000x reference)
//
#include <hip/hip_runtime.h>
#include <hip/hip_bf16.h>
#include <math.h>

typedef __bf16 bf16;
typedef __bf16 bf16x8 __attribute__((ext_vector_type(8)));
typedef __bf16 bf16x4 __attribute__((ext_vector_type(4)));
typedef float f32x4 __attribute__((ext_vector_type(4)));

#define S_ 4096
#define D_ 1024
#define H_ 16
#define HD_ 64
#define N3_ 3072
#define NSPLIT 2

// async global->LDS 16B (m97 pattern)
typedef const __attribute__((address_space(1))) void* gas1_t;
typedef __attribute__((address_space(3))) void* las3_t;
static __device__ __forceinline__ void g2l16(const void* g, void* l) {
  __builtin_amdgcn_global_load_lds((gas1_t)g, (las3_t)l, 16, 0, 0);
}

// ---------------- fused prep: cvt x -> bf16, transpose both weights ----------------
__global__ __launch_bounds__(256) void prep_kernel(const float* __restrict__ x,
                                                   bf16* __restrict__ xb,
                                                   const float* __restrict__ w_qkv,
                                                   bf16* __restrict__ wqkvT,
                                                   const float* __restrict__ w_proj,
                                                   bf16* __restrict__ wprojT) {
  __shared__ float t[32][33];
  const int b = blockIdx.x;
  if (b < 4096) {
    int i = (b * 256 + threadIdx.x) * 4;
    float4 v = *(const float4*)(x + i);
    bf16x4 o;
    o.x = (bf16)v.x; o.y = (bf16)v.y; o.z = (bf16)v.z; o.w = (bf16)v.w;
    *(bf16x4*)(xb + i) = o;
    return;
  }
  const float* in; bf16* outp; int ldin, bx, by;
  if (b < 7168) { int b2 = b - 4096; in = w_qkv;  outp = wqkvT;  ldin = N3_; bx = (b2 % 96) * 32; by = (b2 / 96) * 32; }
  else          { int b3 = b - 7168; in = w_proj; outp = wprojT; ldin = D_;  bx = (b3 % 32) * 32; by = (b3 / 32) * 32; }
  const int tx = threadIdx.x & 31, ty = threadIdx.x >> 5;
#pragma unroll
  for (int i = 0; i < 4; ++i)
    t[ty + i * 8][tx] = in[(size_t)(by + ty + i * 8) * ldin + bx + tx];
  __syncthreads();
#pragma unroll
  for (int i = 0; i < 4; ++i)
    outp[(size_t)(bx + ty + i * 8) * D_ + by + tx] = (bf16)t[tx][ty + i * 8];
}

// ---------------- 8-phase 256x256 QKV GEMM (m201 template, plain HIP) ----------------
// Verified round 6. See round-6 comments for the phase/staging/race analysis.
__global__ __launch_bounds__(512, 2) void gemm256_qkv(const bf16* __restrict__ A,
                                                      const bf16* __restrict__ Bt,
                                                      const float* __restrict__ bias,
                                                      bf16* __restrict__ outb,
                                                      bf16* __restrict__ vTout,
                                                      float qscale) {
  __shared__ bf16 smem[65536];  // 128 KB: [buf 2][A 16384 | B 16384]
  const int K = D_;
  const int NTK = K / 64;  // 16
  const int tid = threadIdx.x;
  const int lane = tid & 63, wv = tid >> 6;
  const int col = lane & 15, quad = lane >> 4;
  const int wr = wv >> 2, wc = wv & 3;
  const long bm = (long)blockIdx.x * 256, bn = (long)blockIdx.y * 256;

  int srowA[2][2], srowB[2][2];
  int schA[2][2], schB[2][2];
#pragma unroll
  for (int q = 0; q < 2; ++q) {
    int slot = q * 512 + tid;
    int rl = slot >> 3, ch = slot & 7;
#pragma unroll
    for (int h = 0; h < 2; ++h) {
      int rowA = (rl & 63) | (h << 6) | ((rl >> 6) << 7);
      srowA[h][q] = rowA; schA[h][q] = ch ^ (rowA & 7);
      int rowB = (rl & 31) | (h << 5) | ((rl >> 5) << 6);
      srowB[h][q] = rowB; schB[h][q] = ch ^ (rowB & 7);
    }
  }
  const int dstoff = tid * 8;

  const int ck[2] = { ((0 * 4 + quad) ^ (col & 7)) * 8, ((1 * 4 + quad) ^ (col & 7)) * 8 };

#define STAGE_A(h, T, buf)                                                        \
  {                                                                               \
    const int kbs = (T) * 64;                                                     \
    bf16* lb = smem + (buf) * 32768 + (h) * 8192;                                 \
    g2l16(A + (bm + srowA[h][0]) * (long)K + kbs + schA[h][0] * 8, lb + dstoff);  \
    g2l16(A + (bm + srowA[h][1]) * (long)K + kbs + schA[h][1] * 8, lb + 4096 + dstoff); \
  }
#define STAGE_B(h, T, buf)                                                        \
  {                                                                               \
    const int kbs = (T) * 64;                                                     \
    bf16* lb = smem + (buf) * 32768 + 16384 + (h) * 8192;                         \
    g2l16(Bt + (bn + srowB[h][0]) * (long)K + kbs + schB[h][0] * 8, lb + dstoff); \
    g2l16(Bt + (bn + srowB[h][1]) * (long)K + kbs + schB[h][1] * 8, lb + 4096 + dstoff); \
  }

  f32x4 acc[8][4] = {};

  STAGE_A(0, 0, 0);
  STAGE_A(1, 0, 0);
  STAGE_B(0, 0, 0);
  STAGE_A(0, 1, 1);
  STAGE_B(1, 0, 0);

  for (int G = 0; G < NTK; ++G) {
    const int cur = G & 1;
    const bf16* bufc = smem + cur * 32768;
    const bool last = (G == NTK - 1);

    bf16x8 afr[4][2], bfr[2][2][2];

    // ---- p0: quadrant (mh0, nh0) ----
    if (last) asm volatile("s_waitcnt vmcnt(2)" ::: "memory");
    else      asm volatile("s_waitcnt vmcnt(4)" ::: "memory");
    __builtin_amdgcn_s_barrier();
    __builtin_amdgcn_sched_barrier(0);
#pragma unroll
    for (int mt = 0; mt < 4; ++mt) {
      const bf16* rp = bufc + (wr * 64 + mt * 16 + col) * 64;
      afr[mt][0] = *(const bf16x8*)(rp + ck[0]);
      afr[mt][1] = *(const bf16x8*)(rp + ck[1]);
    }
#pragma unroll
    for (int nt = 0; nt < 2; ++nt) {
      const bf16* rp = bufc + 16384 + (wc * 32 + nt * 16 + col) * 64;
      bfr[0][nt][0] = *(const bf16x8*)(rp + ck[0]);
      bfr[0][nt][1] = *(const bf16x8*)(rp + ck[1]);
    }
    if (G + 1 < NTK) STAGE_A(1, G + 1, cur ^ 1);
    asm volatile("s_waitcnt lgkmcnt(0)" ::: "memory");
    __builtin_amdgcn_sched_barrier(0);
    __builtin_amdgcn_s_setprio(1);
#pragma unroll
    for (int mt = 0; mt < 4; ++mt)
#pragma unroll
      for (int nt = 0; nt < 2; ++nt) {
        acc[mt][nt] = __builtin_amdgcn_mfma_f32_16x16x32_bf16(afr[mt][0], bfr[0][nt][0], acc[mt][nt], 0, 0, 0);
        acc[mt][nt] = __builtin_amdgcn_mfma_f32_16x16x32_bf16(afr[mt][1], bfr[0][nt][1], acc[mt][nt], 0, 0, 0);
      }
    __builtin_amdgcn_s_setprio(0);

    // ---- p1: quadrant (mh0, nh1) ----
    if (last) asm volatile("s_waitcnt vmcnt(0)" ::: "memory");
    else      asm volatile("s_waitcnt vmcnt(2)" ::: "memory");
    __builtin_amdgcn_s_barrier();
    __builtin_amdgcn_sched_barrier(0);
#pragma unroll
    for (int nt = 0; nt < 2; ++nt) {
      const bf16* rp = bufc + 16384 + 8192 + (wc * 32 + nt * 16 + col) * 64;
      bfr[1][nt][0] = *(const bf16x8*)(rp + ck[0]);
      bfr[1][nt][1] = *(const bf16x8*)(rp + ck[1]);
    }
    if (G + 1 < NTK) STAGE_B(0, G + 1, cur ^ 1);
    asm volatile("s_waitcnt lgkmcnt(0)" ::: "memory");
    __builtin_amdgcn_sched_barrier(0);
    __builtin_amdgcn_s_setprio(1);
#pragma unroll
    for (int mt = 0; mt < 4; ++mt)
#pragma unroll
      for (int nt = 0; nt < 2; ++nt) {
        acc[mt][2 + nt] = __builtin_amdgcn_mfma_f32_16x16x32_bf16(afr[mt][0], bfr[1][nt][0], acc[mt][2 + nt], 0, 0, 0);
        acc[mt][2 + nt] = __builtin_amdgcn_mfma_f32_16x16x32_bf16(afr[mt][1], bfr[1][nt][1], acc[mt][2 + nt], 0, 0, 0);
      }
    __builtin_amdgcn_s_setprio(0);

    // ---- p2: quadrant (mh1, nh1) ----
    __builtin_amdgcn_s_barrier();
    __builtin_amdgcn_sched_barrier(0);
#pragma unroll
    for (int mt = 0; mt < 4; ++mt) {
      const bf16* rp = bufc + 8192 + (wr * 64 + mt * 16 + col) * 64;
      afr[mt][0] = *(const bf16x8*)(rp + ck[0]);
      afr[mt][1] = *(const bf16x8*)(rp + ck[1]);
    }
    if (G + 2 < NTK) STAGE_A(0, G + 2, cur);
    asm volatile("s_waitcnt lgkmcnt(0)" ::: "memory");
    __builtin_amdgcn_sched_barrier(0);
    __builtin_amdgcn_s_setprio(1);
#pragma unroll
    for (int mt = 0; mt < 4; ++mt)
#pragma unroll
      for (int nt = 0; nt < 2; ++nt) {
        acc[4 + mt][2 + nt] = __builtin_amdgcn_mfma_f32_16x16x32_bf16(afr[mt][0], bfr[1][nt][0], acc[4 + mt][2 + nt], 0, 0, 0);
        acc[4 + mt][2 + nt] = __builtin_amdgcn_mfma_f32_16x16x32_bf16(afr[mt][1], bfr[1][nt][1], acc[4 + mt][2 + nt], 0, 0, 0);
      }
    __builtin_amdgcn_s_setprio(0);

    // ---- p3: quadrant (mh1, nh0) ----
    __builtin_amdgcn_s_barrier();
    __builtin_amdgcn_sched_barrier(0);
    if (G + 1 < NTK) STAGE_B(1, G + 1, cur ^ 1);
    __builtin_amdgcn_s_setprio(1);
#pragma unroll
    for (int mt = 0; mt < 4; ++mt)
#pragma unroll
      for (int nt = 0; nt < 2; ++nt) {
        acc[4 + mt][nt] = __builtin_amdgcn_mfma_f32_16x16x32_bf16(afr[mt][0], bfr[0][nt][0], acc[4 + mt][nt], 0, 0, 0);
        acc[4 + mt][nt] = __builtin_amdgcn_mfma_f32_16x16x32_bf16(afr[mt][1], bfr[0][nt][1], acc[4 + mt][nt], 0, 0, 0);
      }
    __builtin_amdgcn_s_setprio(0);
  }

  // ---- epilogue ----
  const bool isV = (blockIdx.y >= 8);
  const bool isQ = (blockIdx.y < 4);
#pragma unroll
  for (int mh = 0; mh < 2; ++mh)
#pragma unroll
    for (int mt = 0; mt < 4; ++mt)
#pragma unroll
      for (int nh = 0; nh < 2; ++nh)
#pragma unroll
        for (int nt = 0; nt < 2; ++nt) {
          long gn = bn + wc * 64 + nh * 32 + nt * 16 + col;
          float bv = bias[gn];
          long gm0 = bm + wr * 128 + mh * 64 + mt * 16 + quad * 4;
          f32x4 a = acc[mh * 4 + mt][nh * 2 + nt];
          if (isV) {
            bf16x4 vv;
#pragma unroll
            for (int i = 0; i < 4; ++i) vv[i] = (bf16)(a[i] + bv);
            *(bf16x4*)(&vTout[(gn - 2 * D_) * (long)S_ + gm0]) = vv;
          } else {
            float sc = isQ ? qscale : 1.0f;
#pragma unroll
            for (int i = 0; i < 4; ++i)
              outb[(gm0 + i) * (long)N3_ + gn] = (bf16)((a[i] + bv) * sc);
          }
        }
#undef STAGE_A
#undef STAGE_B
}

// ---------------- causal flash attention, 2-way K-split, paired chunks ----------------
// CHANGED THIS ROUND: K-fragments read DIRECTLY from global/L2 (addressing
// proven correct in round 5's kernel); sK and the K half of staging deleted.
// Rationale: all 4 waves read IDENTICAL K-frag LDS addresses -> the K LDS
// path was 40 of 80 LDS instrs per block-chunk of pure redundancy. V stays
// LDS-buffered (PV operand, consumed late); the r9 paired structure provides
// the ILP that hides chunk B's K-load latency under chunk A's compute (the
// missing ingredient in round 5's all-global failure). LDS 64->32 KB.
__device__ __forceinline__ int swz_g(int row) {
  return (row & 3) | ((((row >> 2) ^ (row >> 3)) & 1) << 2);
}

__global__ __launch_bounds__(256) void attn_kernel(const bf16* __restrict__ qkv,
                                                   const bf16* __restrict__ vT,
                                                   bf16* __restrict__ Opart,
                                                   float* __restrict__ lws) {
  __shared__ bf16 sV[4][64 * 64];
  const int hh = blockIdx.x;
  const int qb = (int)(gridDim.y - 1 - blockIdx.y);  // heavy blocks dispatch first
  const int sp = blockIdx.z;
  const int tid = threadIdx.x;
  const int wave = tid >> 6, lane = tid & 63;
  const int col = lane & 15, quad = lane >> 4;
  const int qbase = qb * 128 + wave * 32;

  const bf16* qp0 = qkv + (size_t)(qbase + col) * N3_ + hh * HD_;
  bf16x8 aq[2][2];
  aq[0][0] = *(const bf16x8*)(qp0 + quad * 8);
  aq[0][1] = *(const bf16x8*)(qp0 + 32 + quad * 8);
  aq[1][0] = *(const bf16x8*)(qp0 + 16 * N3_ + quad * 8);
  aq[1][1] = *(const bf16x8*)(qp0 + 16 * N3_ + 32 + quad * 8);

  bf16x8 ones;
#pragma unroll
  for (int j = 0; j < 8; ++j) ones[j] = (bf16)1.0f;

  f32x4 acc[2][4] = {};
  f32x4 acc_l[2] = {};

  const bf16* kgbase = qkv + D_ + hh * HD_;
  const bf16* vgbase = vT + (size_t)hh * HD_ * S_;
  const int krow = (col >> 2) * 8 + (col & 3);
  // per-lane loop-invariant K-frag base pointers (round-5 proven addressing)
  const bf16* kp[4];
#pragma unroll
  for (int t = 0; t < 4; ++t)
    kp[t] = kgbase + (size_t)((t >> 1) * 32 + (t & 1) * 4 + krow) * N3_ + quad * 8;

  const int niter = 2 * (qb + 1);            // even
  const int len = niter / NSPLIT;            // qb+1
  const int it0 = sp * len;
  const int it1 = it0 + len;

  const int srow = tid >> 2;
  const int sc0 = (tid & 3) * 2;
  const int gs = swz_g(srow);
  const int soff0 = srow * 64 + ((sc0 ^ gs) * 8);
  const int soff1 = srow * 64 + (((sc0 + 1) ^ gs) * 8);

  // prologue: stage V chunk it0 -> buf0 and it0+1 -> buf1 (if present)
  {
    const bf16* vg = vgbase + (size_t)srow * S_ + it0 * 64 + sc0 * 8;
    *(int4*)(&sV[0][soff0]) = *(const int4*)vg;
    *(int4*)(&sV[0][soff1]) = *(const int4*)(vg + 8);
    if (it0 + 1 < it1) {
      const bf16* vg1 = vg + 64;
      *(int4*)(&sV[1][soff0]) = *(const int4*)vg1;
      *(int4*)(&sV[1][soff1]) = *(const int4*)(vg1 + 8);
    }
  }
  __syncthreads();

// one chunk's full compute; V from LDS buffer BI, K direct from global/L2
#define CHUNK_BODY(KB, BI)                                                        \
  if ((KB) < qbase + 32) {                                                        \
    const bool act0 = (KB) < qbase + 16;                                          \
    const bf16* vc = &sV[BI][0];                                                  \
    const size_t ko = (size_t)(KB) * N3_;                                         \
    f32x4 st[2][4];                                                               \
    _Pragma("unroll")                                                             \
    for (int t = 0; t < 4; ++t) {                                                 \
      bf16x8 kf0 = *(const bf16x8*)(kp[t] + ko);                                  \
      bf16x8 kf1 = *(const bf16x8*)(kp[t] + ko + 32);                             \
      if (act0) {                                                                 \
        f32x4 z = {};                                                             \
        z = __builtin_amdgcn_mfma_f32_16x16x32_bf16(kf0, aq[0][0], z, 0, 0, 0);   \
        st[0][t] = __builtin_amdgcn_mfma_f32_16x16x32_bf16(kf1, aq[0][1], z, 0, 0, 0); \
      }                                                                           \
      f32x4 z = {};                                                               \
      z = __builtin_amdgcn_mfma_f32_16x16x32_bf16(kf0, aq[1][0], z, 0, 0, 0);     \
      st[1][t] = __builtin_amdgcn_mfma_f32_16x16x32_bf16(kf1, aq[1][1], z, 0, 0, 0); \
    }                                                                             \
    bf16x8 pfrag[2][2];                                                           \
    _Pragma("unroll")                                                             \
    for (int s2 = 0; s2 < 2; ++s2) {                                              \
      if (s2 == 0 && !act0) continue;                                             \
      const int rowbase = qbase + 16 * s2;                                        \
      float p[4][4];                                                              \
      if ((KB) + 63 <= rowbase) {                                                 \
        _Pragma("unroll")                                                         \
        for (int t = 0; t < 4; ++t)                                               \
          _Pragma("unroll")                                                       \
          for (int r = 0; r < 4; ++r)                                             \
            p[t][r] = __builtin_amdgcn_exp2f(st[s2][t][r]);                       \
      } else {                                                                    \
        _Pragma("unroll")                                                         \
        for (int t = 0; t < 4; ++t)                                               \
          _Pragma("unroll")                                                       \
          for (int r = 0; r < 4; ++r) {                                           \
            int key = (KB) + (t >> 1) * 32 + quad * 8 + (t & 1) * 4 + r;          \
            p[t][r] = (key > rowbase + col) ? 0.f                                 \
                                            : __builtin_amdgcn_exp2f(st[s2][t][r]); \
          }                                                                       \
      }                                                                           \
      _Pragma("unroll")                                                           \
      for (int c = 0; c < 2; ++c)                                                 \
        _Pragma("unroll")                                                         \
        for (int j2 = 0; j2 < 4; ++j2) {                                          \
          pfrag[s2][c][j2]     = (bf16)p[2 * c][j2];                              \
          pfrag[s2][c][j2 + 4] = (bf16)p[2 * c + 1][j2];                          \
        }                                                                         \
    }                                                                             \
    _Pragma("unroll")                                                             \
    for (int c = 0; c < 2; ++c) {                                                 \
      _Pragma("unroll")                                                           \
      for (int n = 0; n < 4; ++n) {                                               \
        int row = n * 16 + col;                                                   \
        int pc = (4 * c + quad) ^ swz_g(row);                                     \
        bf16x8 vf = *(const bf16x8*)(vc + row * 64 + pc * 8);                     \
        if (act0)                                                                 \
          acc[0][n] = __builtin_amdgcn_mfma_f32_16x16x32_bf16(pfrag[0][c], vf, acc[0][n], 0, 0, 0); \
        acc[1][n] = __builtin_amdgcn_mfma_f32_16x16x32_bf16(pfrag[1][c], vf, acc[1][n], 0, 0, 0);   \
      }                                                                           \
      if (act0)                                                                   \
        acc_l[0] = __builtin_amdgcn_mfma_f32_16x16x32_bf16(pfrag[0][c], ones, acc_l[0], 0, 0, 0);   \
      acc_l[1] = __builtin_amdgcn_mfma_f32_16x16x32_bf16(pfrag[1][c], ones, acc_l[1], 0, 0, 0);     \
    }                                                                             \
  }

  for (int j0 = it0; j0 < it1; j0 += 2) {
    const int bb = (((j0 - it0) >> 1) & 1) * 2;  // buffer pair base: 0 or 2
    const bool hasB = (j0 + 1 < it1);
    const bool pfA = (j0 + 2 < it1);
    const bool pfB = (j0 + 3 < it1);

    // register-prefetch next pair's V
    int4 nv00, nv01, nv10, nv11;
    if (pfA) {
      const bf16* vg = vgbase + (size_t)srow * S_ + (j0 + 2) * 64 + sc0 * 8;
      nv00 = *(const int4*)vg; nv01 = *(const int4*)(vg + 8);
    }
    if (pfB) {
      const bf16* vg = vgbase + (size_t)srow * S_ + (j0 + 3) * 64 + sc0 * 8;
      nv10 = *(const int4*)vg; nv11 = *(const int4*)(vg + 8);
    }

    // compute the pair (chunk B's K-loads are independent -> hoistable ILP)
    {
      const int kb0 = j0 * 64;
      CHUNK_BODY(kb0, bb);
    }
    if (hasB) {
      const int kb1 = (j0 + 1) * 64;
      CHUNK_BODY(kb1, bb + 1);
    }

    // write prefetched V pair into the other buffer pair
    if (pfA) {
      bf16* vn = &sV[bb ^ 2][0];
      *(int4*)(vn + soff0) = nv00; *(int4*)(vn + soff1) = nv01;
    }
    if (pfB) {
      bf16* vn = &sV[(bb ^ 2) + 1][0];
      *(int4*)(vn + soff0) = nv10; *(int4*)(vn + soff1) = nv11;
    }
    __syncthreads();
  }
#undef CHUNK_BODY

  bf16* Op = Opart + (size_t)sp * S_ * D_;
#pragma unroll
  for (int s2 = 0; s2 < 2; ++s2) {
    const int rowbase = qbase + 16 * s2;
    if (col == 0) {
#pragma unroll
      for (int r = 0; r < 4; ++r)
        lws[((size_t)sp * H_ + hh) * S_ + rowbase + quad * 4 + r] = acc_l[s2][r];
    }
#pragma unroll
    for (int n = 0; n < 4; ++n)
#pragma unroll
      for (int r = 0; r < 4; ++r)
        Op[(size_t)(rowbase + quad * 4 + r) * D_ + hh * HD_ + n * 16 + col] =
            (bf16)acc[s2][n][r];
  }
}

// ---------------- combine the two K-split partials (r9 proven) ----------------
__global__ __launch_bounds__(256) void attn_combine(const bf16* __restrict__ Opart,
                                                    const float* __restrict__ lws,
                                                    bf16* __restrict__ outb) {
  int e = (blockIdx.x * 256 + threadIdx.x) * 8;
  int s = e >> 10;
  int h = (e & (D_ - 1)) >> 6;
  float l = 0.f;
#pragma unroll
  for (int sp = 0; sp < NSPLIT; ++sp) l += lws[((size_t)sp * H_ + h) * S_ + s];
  float inv = 1.0f / l;
  float o[8] = {};
#pragma unroll
  for (int sp = 0; sp < NSPLIT; ++sp) {
    bf16x8 a = *(const bf16x8*)(Opart + (size_t)sp * S_ * D_ + e);
#pragma unroll
    for (int j = 0; j < 8; ++j) o[j] += (float)a[j];
  }
  bf16x8 r;
#pragma unroll
  for (int j = 0; j < 8; ++j) r[j] = (bf16)(o[j] * inv);
  *(bf16x8*)(outb + e) = r;
}

// ---------------- 8-phase 128x128 proj GEMM (r11 proven) ----------------
__global__ __launch_bounds__(256, 2) void proj8_gemm(const bf16* __restrict__ A,
                                                     const bf16* __restrict__ Bt,
                                                     const float* __restrict__ bias,
                                                     float* __restrict__ outf) {
  __shared__ bf16 smem[32768];  // 64 KB: [buf 2][A 8192 | B 8192]
  const int K = D_;
  const int NTK = K / 64;  // 16
  const int tid = threadIdx.x;
  const int lane = tid & 63, wv = tid >> 6;
  const int col = lane & 15, quad = lane >> 4;
  const int wr = wv >> 1, wc = wv & 1;
  const long bm = (long)blockIdx.x * 128, bn = (long)blockIdx.y * 128;

  int srow[2][2], sch[2][2];  // [half][q]; same map for A and B (both 128-row)
#pragma unroll
  for (int q = 0; q < 2; ++q) {
    int slot = q * 256 + tid;
    int rl = slot >> 3, ch = slot & 7;
#pragma unroll
    for (int h = 0; h < 2; ++h) {
      int row = (rl & 31) | (h << 5) | ((rl >> 5) << 6);
      srow[h][q] = row; sch[h][q] = ch ^ (row & 7);
    }
  }
  const int dstoff = tid * 8;

  const int ck[2] = { ((0 * 4 + quad) ^ (col & 7)) * 8, ((1 * 4 + quad) ^ (col & 7)) * 8 };

#define STAGE_PA(h, T, buf)                                                      \
  {                                                                              \
    const int kbs = (T) * 64;                                                    \
    bf16* lb = smem + (buf) * 16384 + (h) * 4096;                                \
    g2l16(A + (bm + srow[h][0]) * (long)K + kbs + sch[h][0] * 8, lb + dstoff);   \
    g2l16(A + (bm + srow[h][1]) * (long)K + kbs + sch[h][1] * 8, lb + 2048 + dstoff); \
  }
#define STAGE_PB(h, T, buf)                                                      \
  {                                                                              \
    const int kbs = (T) * 64;                                                    \
    bf16* lb = smem + (buf) * 16384 + 8192 + (h) * 4096;                         \
    g2l16(Bt + (bn + srow[h][0]) * (long)K + kbs + sch[h][0] * 8, lb + dstoff);  \
    g2l16(Bt + (bn + srow[h][1]) * (long)K + kbs + sch[h][1] * 8, lb + 2048 + dstoff); \
  }

  f32x4 acc[4][4] = {};

  STAGE_PA(0, 0, 0);
  STAGE_PA(1, 0, 0);
  STAGE_PB(0, 0, 0);
  STAGE_PA(0, 1, 1);
  STAGE_PB(1, 0, 0);

  for (int G = 0; G < NTK; ++G) {
    const int cur = G & 1;
    const bf16* bufc = smem + cur * 16384;
    const bool last = (G == NTK - 1);

    bf16x8 afr[2][2], bfr[2][2][2];

    // ---- p0: quadrant (mh0, nh0) ----
    if (last) asm volatile("s_waitcnt vmcnt(2)" ::: "memory");
    else      asm volatile("s_waitcnt vmcnt(4)" ::: "memory");
    __builtin_amdgcn_s_barrier();
    __builtin_amdgcn_sched_barrier(0);
#pragma unroll
    for (int mt = 0; mt < 2; ++mt) {
      const bf16* rp = bufc + (wr * 32 + mt * 16 + col) * 64;  // A half0
      afr[mt][0] = *(const bf16x8*)(rp + ck[0]);
      afr[mt][1] = *(const bf16x8*)(rp + ck[1]);
    }
#pragma unroll
    for (int nt = 0; nt < 2; ++nt) {
      const bf16* rp = bufc + 8192 + (wc * 32 + nt * 16 + col) * 64;  // B half0
      bfr[0][nt][0] = *(const bf16x8*)(rp + ck[0]);
      bfr[0][nt][1] = *(const bf16x8*)(rp + ck[1]);
    }
    if (G + 1 < NTK) STAGE_PA(1, G + 1, cur ^ 1);
    asm volatile("s_waitcnt lgkmcnt(0)" ::: "memory");
    __builtin_amdgcn_sched_barrier(0);
    __builtin_amdgcn_s_setprio(1);
#pragma unroll
    for (int mt = 0; mt < 2; ++mt)
#pragma unroll
      for (int nt = 0; nt < 2; ++nt) {
        acc[mt][nt] = __builtin_amdgcn_mfma_f32_16x16x32_bf16(afr[mt][0], bfr[0][nt][0], acc[mt][nt], 0, 0, 0);
        acc[mt][nt] = __builtin_amdgcn_mfma_f32_16x16x32_bf16(afr[mt][1], bfr[0][nt][1], acc[mt][nt], 0, 0, 0);
      }
    __builtin_amdgcn_s_setprio(0);

    // ---- p1: quadrant (mh0, nh1) ----
    if (last) asm volatile("s_waitcnt vmcnt(0)" ::: "memory");
    else      asm volatile("s_waitcnt vmcnt(2)" ::: "memory");
    __builtin_amdgcn_s_barrier();
    __builtin_amdgcn_sched_barrier(0);
#pragma unroll
    for (int nt = 0; nt < 2; ++nt) {
      const bf16* rp = bufc + 8192 + 4096 + (wc * 32 + nt * 16 + col) * 64;  // B half1
      bfr[1][nt][0] = *(const bf16x8*)(rp + ck[0]);
      bfr[1][nt][1] = *(const bf16x8*)(rp + ck[1]);
    }
    if (G + 1 < NTK) STAGE_PB(0, G + 1, cur ^ 1);
    asm volatile("s_waitcnt lgkmcnt(0)" ::: "memory");
    __builtin_amdgcn_sched_barrier(0);
    __builtin_amdgcn_s_setprio(1);
#pragma unroll
    for (int mt = 0; mt < 2; ++mt)
#pragma unroll
      for (int nt = 0; nt < 2; ++nt) {
        acc[mt][2 + nt] = __builtin_amdgcn_mfma_f32_16x16x32_bf16(afr[mt][0], bfr[1][nt][0], acc[mt][2 + nt], 0, 0, 0);
        acc[mt][2 + nt] = __builtin_amdgcn_mfma_f32_16x16x32_bf16(afr[mt][1], bfr[1][nt][1], acc[mt][2 + nt], 0, 0, 0);
      }
    __builtin_amdgcn_s_setprio(0);

    // ---- p2: quadrant (mh1, nh1) ----
    __builtin_amdgcn_s_barrier();
    __builtin_amdgcn_sched_barrier(0);
#pragma unroll
    for (int mt = 0; mt < 2; ++mt) {
      const bf16* rp = bufc + 4096 + (wr * 32 + mt * 16 + col) * 64;  // A half1
      afr[mt][0] = *(const bf16x8*)(rp + ck[0]);
      afr[mt][1] = *(const bf16x8*)(rp + ck[1]);
    }
    if (G + 2 < NTK) STAGE_PA(0, G + 2, cur);
    asm volatile("s_waitcnt lgkmcnt(0)" ::: "memory");
    __builtin_amdgcn_sched_barrier(0);
    __builtin_amdgcn_s_setprio(1);
#pragma unroll
    for (int mt = 0; mt < 2; ++mt)
#pragma unroll
      for (int nt = 0; nt < 2; ++nt) {
        acc[2 + mt][2 + nt] = __builtin_amdgcn_mfma_f32_16x16x32_bf16(afr[mt][0], bfr[1][nt][0], acc[2 + mt][2 + nt], 0, 0, 0);
        acc[2 + mt][2 + nt] = __builtin_amdgcn_mfma_f32_16x16x32_bf16(afr[mt][1], bfr[1][nt][1], acc[2 + mt][2 + nt], 0, 0, 0);
      }
    __builtin_amdgcn_s_setprio(0);

    // ---- p3: quadrant (mh1, nh0) -- no ds_reads ----
    __builtin_amdgcn_s_barrier();
    __builtin_amdgcn_sched_barrier(0);
    if (G + 1 < NTK) STAGE_PB(1, G + 1, cur ^ 1);
    __builtin_amdgcn_s_setprio(1);
#pragma unroll
    for (int mt = 0; mt < 2; ++mt)
#pragma unroll
      for (int nt = 0; nt < 2; ++nt) {
        acc[2 + mt][nt] = __builtin_amdgcn_mfma_f32_16x16x32_bf16(afr[mt][0], bfr[0][nt][0], acc[2 + mt][nt], 0, 0, 0);
        acc[2 + mt][nt] = __builtin_amdgcn_mfma_f32_16x16x32_bf16(afr[mt][1], bfr[0][nt][1], acc[2 + mt][nt], 0, 0, 0);
      }
    __builtin_amdgcn_s_setprio(0);
  }

  // ---- epilogue: f32 out + bias ----
#pragma unroll
  for (int mh = 0; mh < 2; ++mh)
#pragma unroll
    for (int mt = 0; mt < 2; ++mt)
#pragma unroll
      for (int nh = 0; nh < 2; ++nh)
#pragma unroll
        for (int nt = 0; nt < 2; ++nt) {
          long gn = bn + wc * 64 + nh * 32 + nt * 16 + col;
          float bv = bias[gn];
          long gm0 = bm + wr * 64 + mh * 32 + mt * 16 + quad * 4;
          f32x4 a = acc[mh * 2 + mt][nh * 2 + nt];
#pragma unroll
          for (int i = 0; i < 4; ++i)
            outf[(gm0 + i) * (long)D_ + gn] = a[i] + bv;
        }
#undef STAGE_PA
#undef STAGE_PB
}

// ---------------- host orchestration ----------------
extern "C" void kernel_launch(void* const* d_in, const int* in_sizes, int n_in,
                              void* d_out, int out_size, void* d_ws, size_t ws_size,
                              hipStream_t stream) {
  const float* x      = (const float*)d_in[0];
  const float* w_qkv  = (const float*)d_in[1];
  const float* b_qkv  = (const float*)d_in[2];
  const float* w_proj = (const float*)d_in[3];
  const float* b_proj = (const float*)d_in[4];
  float* out = (float*)d_out;

  bf16* xb     = (bf16*)d_ws;                       // [4096][1024]    8 MB (reused as attn)
  bf16* wqkvT  = xb + (size_t)S_ * D_;              // [3072][1024]    6 MB
  bf16* wprojT = wqkvT + (size_t)N3_ * D_;          // [1024][1024]    2 MB
  bf16* qkv    = wprojT + (size_t)D_ * D_;          // [4096][3072]   24 MB (V cols unused)
  bf16* vT     = qkv + (size_t)S_ * N3_;            // [1024][4096]    8 MB
  bf16* Opart  = vT + (size_t)D_ * S_;              // [2][4096][1024] 16 MB
  float* lws   = (float*)(Opart + (size_t)NSPLIT * S_ * D_);  // [2][16][4096] 0.5 MB
  bf16* attn   = xb;  // xb is dead after the QKV GEMM

  const float QSCALE = 0.125f * 1.44269504088896f;  // 1/sqrt(64) * log2(e)

  prep_kernel<<<dim3(8192), 256, 0, stream>>>(x, xb, w_qkv, wqkvT, w_proj, wprojT);
  // QKV GEMM: 8-phase 256x256; Q cols pre-scaled; V cols written transposed to vT
  gemm256_qkv<<<dim3(S_ / 256, N3_ / 256), 512, 0, stream>>>(
      xb, wqkvT, b_qkv, qkv, vT, QSCALE);
  attn_kernel<<<dim3(H_, S_ / 128, NSPLIT), 256, 0, stream>>>(qkv, vT, Opart, lws);
  attn_combine<<<dim3((S_ * D_) / 2048), 256, 0, stream>>>(Opart, lws, attn);
  // proj GEMM: 8-phase 128x128, 256 blocks (r11 proven)
  proj8_gemm<<<dim3(S_ / 128, D_ / 128), 256, 0, stream>>>(
      attn, wprojT, b_proj, out);
}

// Round 13
// 189.654 us; speedup vs baseline: 1.1385x; 1.1385x over previous
//
#include <hip/hip_runtime.h>
#include <hip/hip_bf16.h>
#include <math.h>

typedef __bf16 bf16;
typedef __bf16 bf16x8 __attribute__((ext_vector_type(8)));
typedef __bf16 bf16x4 __attribute__((ext_vector_type(4)));
typedef float f32x4 __attribute__((ext_vector_type(4)));

#define S_ 4096
#define D_ 1024
#define H_ 16
#define HD_ 64
#define N3_ 3072
#define NSPLIT 2

// async global->LDS 16B (m97 pattern)
typedef const __attribute__((address_space(1))) void* gas1_t;
typedef __attribute__((address_space(3))) void* las3_t;
static __device__ __forceinline__ void g2l16(const void* g, void* l) {
  __builtin_amdgcn_global_load_lds((gas1_t)g, (las3_t)l, 16, 0, 0);
}

// ---------------- fused prep: cvt x -> bf16, transpose both weights ----------------
__global__ __launch_bounds__(256) void prep_kernel(const float* __restrict__ x,
                                                   bf16* __restrict__ xb,
                                                   const float* __restrict__ w_qkv,
                                                   bf16* __restrict__ wqkvT,
                                                   const float* __restrict__ w_proj,
                                                   bf16* __restrict__ wprojT) {
  __shared__ float t[32][33];
  const int b = blockIdx.x;
  if (b < 4096) {
    int i = (b * 256 + threadIdx.x) * 4;
    float4 v = *(const float4*)(x + i);
    bf16x4 o;
    o.x = (bf16)v.x; o.y = (bf16)v.y; o.z = (bf16)v.z; o.w = (bf16)v.w;
    *(bf16x4*)(xb + i) = o;
    return;
  }
  const float* in; bf16* outp; int ldin, bx, by;
  if (b < 7168) { int b2 = b - 4096; in = w_qkv;  outp = wqkvT;  ldin = N3_; bx = (b2 % 96) * 32; by = (b2 / 96) * 32; }
  else          { int b3 = b - 7168; in = w_proj; outp = wprojT; ldin = D_;  bx = (b3 % 32) * 32; by = (b3 / 32) * 32; }
  const int tx = threadIdx.x & 31, ty = threadIdx.x >> 5;
#pragma unroll
  for (int i = 0; i < 4; ++i)
    t[ty + i * 8][tx] = in[(size_t)(by + ty + i * 8) * ldin + bx + tx];
  __syncthreads();
#pragma unroll
  for (int i = 0; i < 4; ++i)
    outp[(size_t)(bx + ty + i * 8) * D_ + by + tx] = (bf16)t[tx][ty + i * 8];
}

// ---------------- 8-phase 256x256 QKV GEMM (m201 template, plain HIP) ----------------
__global__ __launch_bounds__(512, 2) void gemm256_qkv(const bf16* __restrict__ A,
                                                      const bf16* __restrict__ Bt,
                                                      const float* __restrict__ bias,
                                                      bf16* __restrict__ outb,
                                                      bf16* __restrict__ vTout,
                                                      float qscale) {
  __shared__ bf16 smem[65536];  // 128 KB: [buf 2][A 16384 | B 16384]
  const int K = D_;
  const int NTK = K / 64;  // 16
  const int tid = threadIdx.x;
  const int lane = tid & 63, wv = tid >> 6;
  const int col = lane & 15, quad = lane >> 4;
  const int wr = wv >> 2, wc = wv & 3;
  const long bm = (long)blockIdx.x * 256, bn = (long)blockIdx.y * 256;

  int srowA[2][2], srowB[2][2];
  int schA[2][2], schB[2][2];
#pragma unroll
  for (int q = 0; q < 2; ++q) {
    int slot = q * 512 + tid;
    int rl = slot >> 3, ch = slot & 7;
#pragma unroll
    for (int h = 0; h < 2; ++h) {
      int rowA = (rl & 63) | (h << 6) | ((rl >> 6) << 7);
      srowA[h][q] = rowA; schA[h][q] = ch ^ (rowA & 7);
      int rowB = (rl & 31) | (h << 5) | ((rl >> 5) << 6);
      srowB[h][q] = rowB; schB[h][q] = ch ^ (rowB & 7);
    }
  }
  const int dstoff = tid * 8;

  const int ck[2] = { ((0 * 4 + quad) ^ (col & 7)) * 8, ((1 * 4 + quad) ^ (col & 7)) * 8 };

#define STAGE_A(h, T, buf)                                                        \
  {                                                                               \
    const int kbs = (T) * 64;                                                     \
    bf16* lb = smem + (buf) * 32768 + (h) * 8192;                                 \
    g2l16(A + (bm + srowA[h][0]) * (long)K + kbs + schA[h][0] * 8, lb + dstoff);  \
    g2l16(A + (bm + srowA[h][1]) * (long)K + kbs + schA[h][1] * 8, lb + 4096 + dstoff); \
  }
#define STAGE_B(h, T, buf)                                                        \
  {                                                                               \
    const int kbs = (T) * 64;                                                     \
    bf16* lb = smem + (buf) * 32768 + 16384 + (h) * 8192;                         \
    g2l16(Bt + (bn + srowB[h][0]) * (long)K + kbs + schB[h][0] * 8, lb + dstoff); \
    g2l16(Bt + (bn + srowB[h][1]) * (long)K + kbs + schB[h][1] * 8, lb + 4096 + dstoff); \
  }

  f32x4 acc[8][4] = {};

  STAGE_A(0, 0, 0);
  STAGE_A(1, 0, 0);
  STAGE_B(0, 0, 0);
  STAGE_A(0, 1, 1);
  STAGE_B(1, 0, 0);

  for (int G = 0; G < NTK; ++G) {
    const int cur = G & 1;
    const bf16* bufc = smem + cur * 32768;
    const bool last = (G == NTK - 1);

    bf16x8 afr[4][2], bfr[2][2][2];

    // ---- p0: quadrant (mh0, nh0) ----
    if (last) asm volatile("s_waitcnt vmcnt(2)" ::: "memory");
    else      asm volatile("s_waitcnt vmcnt(4)" ::: "memory");
    __builtin_amdgcn_s_barrier();
    __builtin_amdgcn_sched_barrier(0);
#pragma unroll
    for (int mt = 0; mt < 4; ++mt) {
      const bf16* rp = bufc + (wr * 64 + mt * 16 + col) * 64;
      afr[mt][0] = *(const bf16x8*)(rp + ck[0]);
      afr[mt][1] = *(const bf16x8*)(rp + ck[1]);
    }
#pragma unroll
    for (int nt = 0; nt < 2; ++nt) {
      const bf16* rp = bufc + 16384 + (wc * 32 + nt * 16 + col) * 64;
      bfr[0][nt][0] = *(const bf16x8*)(rp + ck[0]);
      bfr[0][nt][1] = *(const bf16x8*)(rp + ck[1]);
    }
    if (G + 1 < NTK) STAGE_A(1, G + 1, cur ^ 1);
    asm volatile("s_waitcnt lgkmcnt(0)" ::: "memory");
    __builtin_amdgcn_sched_barrier(0);
    __builtin_amdgcn_s_setprio(1);
#pragma unroll
    for (int mt = 0; mt < 4; ++mt)
#pragma unroll
      for (int nt = 0; nt < 2; ++nt) {
        acc[mt][nt] = __builtin_amdgcn_mfma_f32_16x16x32_bf16(afr[mt][0], bfr[0][nt][0], acc[mt][nt], 0, 0, 0);
        acc[mt][nt] = __builtin_amdgcn_mfma_f32_16x16x32_bf16(afr[mt][1], bfr[0][nt][1], acc[mt][nt], 0, 0, 0);
      }
    __builtin_amdgcn_s_setprio(0);

    // ---- p1: quadrant (mh0, nh1) ----
    if (last) asm volatile("s_waitcnt vmcnt(0)" ::: "memory");
    else      asm volatile("s_waitcnt vmcnt(2)" ::: "memory");
    __builtin_amdgcn_s_barrier();
    __builtin_amdgcn_sched_barrier(0);
#pragma unroll
    for (int nt = 0; nt < 2; ++nt) {
      const bf16* rp = bufc + 16384 + 8192 + (wc * 32 + nt * 16 + col) * 64;
      bfr[1][nt][0] = *(const bf16x8*)(rp + ck[0]);
      bfr[1][nt][1] = *(const bf16x8*)(rp + ck[1]);
    }
    if (G + 1 < NTK) STAGE_B(0, G + 1, cur ^ 1);
    asm volatile("s_waitcnt lgkmcnt(0)" ::: "memory");
    __builtin_amdgcn_sched_barrier(0);
    __builtin_amdgcn_s_setprio(1);
#pragma unroll
    for (int mt = 0; mt < 4; ++mt)
#pragma unroll
      for (int nt = 0; nt < 2; ++nt) {
        acc[mt][2 + nt] = __builtin_amdgcn_mfma_f32_16x16x32_bf16(afr[mt][0], bfr[1][nt][0], acc[mt][2 + nt], 0, 0, 0);
        acc[mt][2 + nt] = __builtin_amdgcn_mfma_f32_16x16x32_bf16(afr[mt][1], bfr[1][nt][1], acc[mt][2 + nt], 0, 0, 0);
      }
    __builtin_amdgcn_s_setprio(0);

    // ---- p2: quadrant (mh1, nh1) ----
    __builtin_amdgcn_s_barrier();
    __builtin_amdgcn_sched_barrier(0);
#pragma unroll
    for (int mt = 0; mt < 4; ++mt) {
      const bf16* rp = bufc + 8192 + (wr * 64 + mt * 16 + col) * 64;
      afr[mt][0] = *(const bf16x8*)(rp + ck[0]);
      afr[mt][1] = *(const bf16x8*)(rp + ck[1]);
    }
    if (G + 2 < NTK) STAGE_A(0, G + 2, cur);
    asm volatile("s_waitcnt lgkmcnt(0)" ::: "memory");
    __builtin_amdgcn_sched_barrier(0);
    __builtin_amdgcn_s_setprio(1);
#pragma unroll
    for (int mt = 0; mt < 4; ++mt)
#pragma unroll
      for (int nt = 0; nt < 2; ++nt) {
        acc[4 + mt][2 + nt] = __builtin_amdgcn_mfma_f32_16x16x32_bf16(afr[mt][0], bfr[1][nt][0], acc[4 + mt][2 + nt], 0, 0, 0);
        acc[4 + mt][2 + nt] = __builtin_amdgcn_mfma_f32_16x16x32_bf16(afr[mt][1], bfr[1][nt][1], acc[4 + mt][2 + nt], 0, 0, 0);
      }
    __builtin_amdgcn_s_setprio(0);

    // ---- p3: quadrant (mh1, nh0) ----
    __builtin_amdgcn_s_barrier();
    __builtin_amdgcn_sched_barrier(0);
    if (G + 1 < NTK) STAGE_B(1, G + 1, cur ^ 1);
    __builtin_amdgcn_s_setprio(1);
#pragma unroll
    for (int mt = 0; mt < 4; ++mt)
#pragma unroll
      for (int nt = 0; nt < 2; ++nt) {
        acc[4 + mt][nt] = __builtin_amdgcn_mfma_f32_16x16x32_bf16(afr[mt][0], bfr[0][nt][0], acc[4 + mt][nt], 0, 0, 0);
        acc[4 + mt][nt] = __builtin_amdgcn_mfma_f32_16x16x32_bf16(afr[mt][1], bfr[0][nt][1], acc[4 + mt][nt], 0, 0, 0);
      }
    __builtin_amdgcn_s_setprio(0);
  }

  // ---- epilogue ----
  const bool isV = (blockIdx.y >= 8);
  const bool isQ = (blockIdx.y < 4);
#pragma unroll
  for (int mh = 0; mh < 2; ++mh)
#pragma unroll
    for (int mt = 0; mt < 4; ++mt)
#pragma unroll
      for (int nh = 0; nh < 2; ++nh)
#pragma unroll
        for (int nt = 0; nt < 2; ++nt) {
          long gn = bn + wc * 64 + nh * 32 + nt * 16 + col;
          float bv = bias[gn];
          long gm0 = bm + wr * 128 + mh * 64 + mt * 16 + quad * 4;
          f32x4 a = acc[mh * 4 + mt][nh * 2 + nt];
          if (isV) {
            bf16x4 vv;
#pragma unroll
            for (int i = 0; i < 4; ++i) vv[i] = (bf16)(a[i] + bv);
            *(bf16x4*)(&vTout[(gn - 2 * D_) * (long)S_ + gm0]) = vv;
          } else {
            float sc = isQ ? qscale : 1.0f;
#pragma unroll
            for (int i = 0; i < 4; ++i)
              outb[(gm0 + i) * (long)N3_ + gn] = (bf16)((a[i] + bv) * sc);
          }
        }
#undef STAGE_A
#undef STAGE_B
}

// ---------------- causal flash attention, 2-way K-split, paired chunks ----------------
// r9-proven core (K AND V in LDS). NEW: 1-D grid, XCD-aware head grouping
// (heads {2x,2x+1} -> XCD x for L2-resident K/V); heavy-first preserved.
__device__ __forceinline__ int swz_g(int row) {
  return (row & 3) | ((((row >> 2) ^ (row >> 3)) & 1) << 2);
}

__global__ __launch_bounds__(256) void attn_kernel(const bf16* __restrict__ qkv,
                                                   const bf16* __restrict__ vT,
                                                   bf16* __restrict__ Opart,
                                                   float* __restrict__ lws) {
  __shared__ bf16 sK[4][64 * 64];
  __shared__ bf16 sV[4][64 * 64];
  const int bid = blockIdx.x;
  const int wgid = (bid & 7) * 128 + (bid >> 3);
  const int hh = wgid >> 6;
  const int rem = wgid & 63;
  const int qb = 31 - (rem >> 1);
  const int sp = rem & 1;
  const int tid = threadIdx.x;
  const int wave = tid >> 6, lane = tid & 63;
  const int col = lane & 15, quad = lane >> 4;
  const int qbase = qb * 128 + wave * 32;

  const bf16* qp0 = qkv + (size_t)(qbase + col) * N3_ + hh * HD_;
  bf16x8 aq[2][2];
  aq[0][0] = *(const bf16x8*)(qp0 + quad * 8);
  aq[0][1] = *(const bf16x8*)(qp0 + 32 + quad * 8);
  aq[1][0] = *(const bf16x8*)(qp0 + 16 * N3_ + quad * 8);
  aq[1][1] = *(const bf16x8*)(qp0 + 16 * N3_ + 32 + quad * 8);

  bf16x8 ones;
#pragma unroll
  for (int j = 0; j < 8; ++j) ones[j] = (bf16)1.0f;

  f32x4 acc[2][4] = {};
  f32x4 acc_l[2] = {};

  const bf16* kgbase = qkv + D_ + hh * HD_;
  const bf16* vgbase = vT + (size_t)hh * HD_ * S_;
  const int krow = (col >> 2) * 8 + (col & 3);
  const int niter = 2 * (qb + 1);            // even
  const int len = niter / NSPLIT;            // qb+1
  const int it0 = sp * len;
  const int it1 = it0 + len;

  const int srow = tid >> 2;
  const int sc0 = (tid & 3) * 2;
  const int gs = swz_g(srow);
  const int soff0 = srow * 64 + ((sc0 ^ gs) * 8);
  const int soff1 = srow * 64 + (((sc0 + 1) ^ gs) * 8);

  // prologue: stage chunk it0 -> buf0 and it0+1 -> buf1 (if present)
  {
    const bf16* kg = kgbase + (size_t)(it0 * 64 + srow) * N3_ + sc0 * 8;
    const bf16* vg = vgbase + (size_t)srow * S_ + it0 * 64 + sc0 * 8;
    *(int4*)(&sK[0][soff0]) = *(const int4*)kg;
    *(int4*)(&sK[0][soff1]) = *(const int4*)(kg + 8);
    *(int4*)(&sV[0][soff0]) = *(const int4*)vg;
    *(int4*)(&sV[0][soff1]) = *(const int4*)(vg + 8);
    if (it0 + 1 < it1) {
      const bf16* kg1 = kg + (size_t)64 * N3_;
      const bf16* vg1 = vg + 64;
      *(int4*)(&sK[1][soff0]) = *(const int4*)kg1;
      *(int4*)(&sK[1][soff1]) = *(const int4*)(kg1 + 8);
      *(int4*)(&sV[1][soff0]) = *(const int4*)vg1;
      *(int4*)(&sV[1][soff1]) = *(const int4*)(vg1 + 8);
    }
  }
  __syncthreads();

// one chunk's full compute (round-0 proven body), reading LDS buffer BI
#define CHUNK_BODY(KB, BI)                                                        \
  if ((KB) < qbase + 32) {                                                        \
    const bool act0 = (KB) < qbase + 16;                                          \
    const bf16* kc = &sK[BI][0];                                                  \
    const bf16* vc = &sV[BI][0];                                                  \
    f32x4 st[2][4];                                                               \
    _Pragma("unroll")                                                             \
    for (int t = 0; t < 4; ++t) {                                                 \
      int row = (t >> 1) * 32 + (t & 1) * 4 + krow;                               \
      int pc = quad ^ swz_g(row);                                                 \
      bf16x8 kf0 = *(const bf16x8*)(kc + row * 64 + pc * 8);                      \
      bf16x8 kf1 = *(const bf16x8*)(kc + row * 64 + (pc ^ 4) * 8);                \
      if (act0) {                                                                 \
        f32x4 z = {};                                                             \
        z = __builtin_amdgcn_mfma_f32_16x16x32_bf16(kf0, aq[0][0], z, 0, 0, 0);   \
        st[0][t] = __builtin_amdgcn_mfma_f32_16x16x32_bf16(kf1, aq[0][1], z, 0, 0, 0); \
      }                                                                           \
      f32x4 z = {};                                                               \
      z = __builtin_amdgcn_mfma_f32_16x16x32_bf16(kf0, aq[1][0], z, 0, 0, 0);     \
      st[1][t] = __builtin_amdgcn_mfma_f32_16x16x32_bf16(kf1, aq[1][1], z, 0, 0, 0); \
    }                                                                             \
    bf16x8 pfrag[2][2];                                                           \
    _Pragma("unroll")                                                             \
    for (int s2 = 0; s2 < 2; ++s2) {                                              \
      if (s2 == 0 && !act0) continue;                                             \
      const int rowbase = qbase + 16 * s2;                                        \
      float p[4][4];                                                              \
      if ((KB) + 63 <= rowbase) {                                                 \
        _Pragma("unroll")                                                         \
        for (int t = 0; t < 4; ++t)                                               \
          _Pragma("unroll")                                                       \
          for (int r = 0; r < 4; ++r)                                             \
            p[t][r] = __builtin_amdgcn_exp2f(st[s2][t][r]);                       \
      } else {                                                                    \
        _Pragma("unroll")                                                         \
        for (int t = 0; t < 4; ++t)                                               \
          _Pragma("unroll")                                                       \
          for (int r = 0; r < 4; ++r) {                                           \
            int key = (KB) + (t >> 1) * 32 + quad * 8 + (t & 1) * 4 + r;          \
            p[t][r] = (key > rowbase + col) ? 0.f                                 \
                                            : __builtin_amdgcn_exp2f(st[s2][t][r]); \
          }                                                                       \
      }                                                                           \
      _Pragma("unroll")                                                           \
      for (int c = 0; c < 2; ++c)                                                 \
        _Pragma("unroll")                                                         \
        for (int j2 = 0; j2 < 4; ++j2) {                                          \
          pfrag[s2][c][j2]     = (bf16)p[2 * c][j2];                              \
          pfrag[s2][c][j2 + 4] = (bf16)p[2 * c + 1][j2];                          \
        }                                                                         \
    }                                                                             \
    _Pragma("unroll")                                                             \
    for (int c = 0; c < 2; ++c) {                                                 \
      _Pragma("unroll")                                                           \
      for (int n = 0; n < 4; ++n) {                                               \
        int row = n * 16 + col;                                                   \
        int pc = (4 * c + quad) ^ swz_g(row);                                     \
        bf16x8 vf = *(const bf16x8*)(vc + row * 64 + pc * 8);                     \
        if (act0)                                                                 \
          acc[0][n] = __builtin_amdgcn_mfma_f32_16x16x32_bf16(pfrag[0][c], vf, acc[0][n], 0, 0, 0); \
        acc[1][n] = __builtin_amdgcn_mfma_f32_16x16x32_bf16(pfrag[1][c], vf, acc[1][n], 0, 0, 0);   \
      }                                                                           \
      if (act0)                                                                   \
        acc_l[0] = __builtin_amdgcn_mfma_f32_16x16x32_bf16(pfrag[0][c], ones, acc_l[0], 0, 0, 0);   \
      acc_l[1] = __builtin_amdgcn_mfma_f32_16x16x32_bf16(pfrag[1][c], ones, acc_l[1], 0, 0, 0);     \
    }                                                                             \
  }

  for (int j0 = it0; j0 < it1; j0 += 2) {
    const int bb = (((j0 - it0) >> 1) & 1) * 2;  // buffer pair base: 0 or 2
    const bool hasB = (j0 + 1 < it1);
    const bool pfA = (j0 + 2 < it1);
    const bool pfB = (j0 + 3 < it1);

    // register-prefetch next pair
    int4 nk00, nk01, nv00, nv01, nk10, nk11, nv10, nv11;
    if (pfA) {
      const bf16* kg = kgbase + (size_t)((j0 + 2) * 64 + srow) * N3_ + sc0 * 8;
      const bf16* vg = vgbase + (size_t)srow * S_ + (j0 + 2) * 64 + sc0 * 8;
      nk00 = *(const int4*)kg; nk01 = *(const int4*)(kg + 8);
      nv00 = *(const int4*)vg; nv01 = *(const int4*)(vg + 8);
    }
    if (pfB) {
      const bf16* kg = kgbase + (size_t)((j0 + 3) * 64 + srow) * N3_ + sc0 * 8;
      const bf16* vg = vgbase + (size_t)srow * S_ + (j0 + 3) * 64 + sc0 * 8;
      nk10 = *(const int4*)kg; nk11 = *(const int4*)(kg + 8);
      nv10 = *(const int4*)vg; nv11 = *(const int4*)(vg + 8);
    }

    // compute the pair (independent streams for the scheduler)
    {
      const int kb0 = j0 * 64;
      CHUNK_BODY(kb0, bb);
    }
    if (hasB) {
      const int kb1 = (j0 + 1) * 64;
      CHUNK_BODY(kb1, bb + 1);
    }

    // write prefetched pair into the other buffer pair
    if (pfA) {
      bf16* kn = &sK[bb ^ 2][0];
      bf16* vn = &sV[bb ^ 2][0];
      *(int4*)(kn + soff0) = nk00; *(int4*)(kn + soff1) = nk01;
      *(int4*)(vn + soff0) = nv00; *(int4*)(vn + soff1) = nv01;
    }
    if (pfB) {
      bf16* kn = &sK[(bb ^ 2) + 1][0];
      bf16* vn = &sV[(bb ^ 2) + 1][0];
      *(int4*)(kn + soff0) = nk10; *(int4*)(kn + soff1) = nk11;
      *(int4*)(vn + soff0) = nv10; *(int4*)(vn + soff1) = nv11;
    }
    __syncthreads();
  }
#undef CHUNK_BODY

  bf16* Op = Opart + (size_t)sp * S_ * D_;
#pragma unroll
  for (int s2 = 0; s2 < 2; ++s2) {
    const int rowbase = qbase + 16 * s2;
    if (col == 0) {
#pragma unroll
      for (int r = 0; r < 4; ++r)
        lws[((size_t)sp * H_ + hh) * S_ + rowbase + quad * 4 + r] = acc_l[s2][r];
    }
#pragma unroll
    for (int n = 0; n < 4; ++n)
#pragma unroll
      for (int r = 0; r < 4; ++r)
        Op[(size_t)(rowbase + quad * 4 + r) * D_ + hh * HD_ + n * 16 + col] =
            (bf16)acc[s2][n][r];
  }
}

// ---------------- combine the two K-split partials (r9 proven) ----------------
__global__ __launch_bounds__(256) void attn_combine(const bf16* __restrict__ Opart,
                                                    const float* __restrict__ lws,
                                                    bf16* __restrict__ outb) {
  int e = (blockIdx.x * 256 + threadIdx.x) * 8;
  int s = e >> 10;
  int h = (e & (D_ - 1)) >> 6;
  float l = 0.f;
#pragma unroll
  for (int sp = 0; sp < NSPLIT; ++sp) l += lws[((size_t)sp * H_ + h) * S_ + s];
  float inv = 1.0f / l;
  float o[8] = {};
#pragma unroll
  for (int sp = 0; sp < NSPLIT; ++sp) {
    bf16x8 a = *(const bf16x8*)(Opart + (size_t)sp * S_ * D_ + e);
#pragma unroll
    for (int j = 0; j < 8; ++j) o[j] += (float)a[j];
  }
  bf16x8 r;
#pragma unroll
  for (int j = 0; j < 8; ++j) r[j] = (bf16)(o[j] * inv);
  *(bf16x8*)(outb + e) = r;
}

// ---------------- 8-phase 128x128 proj GEMM (r11 proven) ----------------
__global__ __launch_bounds__(256, 2) void proj8_gemm(const bf16* __restrict__ A,
                                                     const bf16* __restrict__ Bt,
                                                     const float* __restrict__ bias,
                                                     float* __restrict__ outf) {
  __shared__ bf16 smem[32768];  // 64 KB: [buf 2][A 8192 | B 8192]
  const int K = D_;
  const int NTK = K / 64;  // 16
  const int tid = threadIdx.x;
  const int lane = tid & 63, wv = tid >> 6;
  const int col = lane & 15, quad = lane >> 4;
  const int wr = wv >> 1, wc = wv & 1;
  const long bm = (long)blockIdx.x * 128, bn = (long)blockIdx.y * 128;

  int srow[2][2], sch[2][2];
#pragma unroll
  for (int q = 0; q < 2; ++q) {
    int slot = q * 256 + tid;
    int rl = slot >> 3, ch = slot & 7;
#pragma unroll
    for (int h = 0; h < 2; ++h) {
      int row = (rl & 31) | (h << 5) | ((rl >> 5) << 6);
      srow[h][q] = row; sch[h][q] = ch ^ (row & 7);
    }
  }
  const int dstoff = tid * 8;

  const int ck[2] = { ((0 * 4 + quad) ^ (col & 7)) * 8, ((1 * 4 + quad) ^ (col & 7)) * 8 };

#define STAGE_PA(h, T, buf)                                                      \
  {                                                                              \
    const int kbs = (T) * 64;                                                    \
    bf16* lb = smem + (buf) * 16384 + (h) * 4096;                                \
    g2l16(A + (bm + srow[h][0]) * (long)K + kbs + sch[h][0] * 8, lb + dstoff);   \
    g2l16(A + (bm + srow[h][1]) * (long)K + kbs + sch[h][1] * 8, lb + 2048 + dstoff); \
  }
#define STAGE_PB(h, T, buf)                                                      \
  {                                                                              \
    const int kbs = (T) * 64;                                                    \
    bf16* lb = smem + (buf) * 16384 + 8192 + (h) * 4096;                         \
    g2l16(Bt + (bn + srow[h][0]) * (long)K + kbs + sch[h][0] * 8, lb + dstoff);  \
    g2l16(Bt + (bn + srow[h][1]) * (long)K + kbs + sch[h][1] * 8, lb + 2048 + dstoff); \
  }

  f32x4 acc[4][4] = {};

  STAGE_PA(0, 0, 0);
  STAGE_PA(1, 0, 0);
  STAGE_PB(0, 0, 0);
  STAGE_PA(0, 1, 1);
  STAGE_PB(1, 0, 0);

  for (int G = 0; G < NTK; ++G) {
    const int cur = G & 1;
    const bf16* bufc = smem + cur * 16384;
    const bool last = (G == NTK - 1);

    bf16x8 afr[2][2], bfr[2][2][2];

    if (last) asm volatile("s_waitcnt vmcnt(2)" ::: "memory");
    else      asm volatile("s_waitcnt vmcnt(4)" ::: "memory");
    __builtin_amdgcn_s_barrier();
    __builtin_amdgcn_sched_barrier(0);
#pragma unroll
    for (int mt = 0; mt < 2; ++mt) {
      const bf16* rp = bufc + (wr * 32 + mt * 16 + col) * 64;
      afr[mt][0] = *(const bf16x8*)(rp + ck[0]);
      afr[mt][1] = *(const bf16x8*)(rp + ck[1]);
    }
#pragma unroll
    for (int nt = 0; nt < 2; ++nt) {
      const bf16* rp = bufc + 8192 + (wc * 32 + nt * 16 + col) * 64;
      bfr[0][nt][0] = *(const bf16x8*)(rp + ck[0]);
      bfr[0][nt][1] = *(const bf16x8*)(rp + ck[1]);
    }
    if (G + 1 < NTK) STAGE_PA(1, G + 1, cur ^ 1);
    asm volatile("s_waitcnt lgkmcnt(0)" ::: "memory");
    __builtin_amdgcn_sched_barrier(0);
    __builtin_amdgcn_s_setprio(1);
#pragma unroll
    for (int mt = 0; mt < 2; ++mt)
#pragma unroll
      for (int nt = 0; nt < 2; ++nt) {
        acc[mt][nt] = __builtin_amdgcn_mfma_f32_16x16x32_bf16(afr[mt][0], bfr[0][nt][0], acc[mt][nt], 0, 0, 0);
        acc[mt][nt] = __builtin_amdgcn_mfma_f32_16x16x32_bf16(afr[mt][1], bfr[0][nt][1], acc[mt][nt], 0, 0, 0);
      }
    __builtin_amdgcn_s_setprio(0);

    if (last) asm volatile("s_waitcnt vmcnt(0)" ::: "memory");
    else      asm volatile("s_waitcnt vmcnt(2)" ::: "memory");
    __builtin_amdgcn_s_barrier();
    __builtin_amdgcn_sched_barrier(0);
#pragma unroll
    for (int nt = 0; nt < 2; ++nt) {
      const bf16* rp = bufc + 8192 + 4096 + (wc * 32 + nt * 16 + col) * 64;
      bfr[1][nt][0] = *(const bf16x8*)(rp + ck[0]);
      bfr[1][nt][1] = *(const bf16x8*)(rp + ck[1]);
    }
    if (G + 1 < NTK) STAGE_PB(0, G + 1, cur ^ 1);
    asm volatile("s_waitcnt lgkmcnt(0)" ::: "memory");
    __builtin_amdgcn_sched_barrier(0);
    __builtin_amdgcn_s_setprio(1);
#pragma unroll
    for (int mt = 0; mt < 2; ++mt)
#pragma unroll
      for (int nt = 0; nt < 2; ++nt) {
        acc[mt][2 + nt] = __builtin_amdgcn_mfma_f32_16x16x32_bf16(afr[mt][0], bfr[1][nt][0], acc[mt][2 + nt], 0, 0, 0);
        acc[mt][2 + nt] = __builtin_amdgcn_mfma_f32_16x16x32_bf16(afr[mt][1], bfr[1][nt][1], acc[mt][2 + nt], 0, 0, 0);
      }
    __builtin_amdgcn_s_setprio(0);

    __builtin_amdgcn_s_barrier();
    __builtin_amdgcn_sched_barrier(0);
#pragma unroll
    for (int mt = 0; mt < 2; ++mt) {
      const bf16* rp = bufc + 4096 + (wr * 32 + mt * 16 + col) * 64;
      afr[mt][0] = *(const bf16x8*)(rp + ck[0]);
      afr[mt][1] = *(const bf16x8*)(rp + ck[1]);
    }
    if (G + 2 < NTK) STAGE_PA(0, G + 2, cur);
    asm volatile("s_waitcnt lgkmcnt(0)" ::: "memory");
    __builtin_amdgcn_sched_barrier(0);
    __builtin_amdgcn_s_setprio(1);
#pragma unroll
    for (int mt = 0; mt < 2; ++mt)
#pragma unroll
      for (int nt = 0; nt < 2; ++nt) {
        acc[2 + mt][2 + nt] = __builtin_amdgcn_mfma_f32_16x16x32_bf16(afr[mt][0], bfr[1][nt][0], acc[2 + mt][2 + nt], 0, 0, 0);
        acc[2 + mt][2 + nt] = __builtin_amdgcn_mfma_f32_16x16x32_bf16(afr[mt][1], bfr[1][nt][1], acc[2 + mt][2 + nt], 0, 0, 0);
      }
    __builtin_amdgcn_s_setprio(0);

    __builtin_amdgcn_s_barrier();
    __builtin_amdgcn_sched_barrier(0);
    if (G + 1 < NTK) STAGE_PB(1, G + 1, cur ^ 1);
    __builtin_amdgcn_s_setprio(1);
#pragma unroll
    for (int mt = 0; mt < 2; ++mt)
#pragma unroll
      for (int nt = 0; nt < 2; ++nt) {
        acc[2 + mt][nt] = __builtin_amdgcn_mfma_f32_16x16x32_bf16(afr[mt][0], bfr[0][nt][0], acc[2 + mt][nt], 0, 0, 0);
        acc[2 + mt][nt] = __builtin_amdgcn_mfma_f32_16x16x32_bf16(afr[mt][1], bfr[0][nt][1], acc[2 + mt][nt], 0, 0, 0);
      }
    __builtin_amdgcn_s_setprio(0);
  }

#pragma unroll
  for (int mh = 0; mh < 2; ++mh)
#pragma unroll
    for (int mt = 0; mt < 2; ++mt)
#pragma unroll
      for (int nh = 0; nh < 2; ++nh)
#pragma unroll
        for (int nt = 0; nt < 2; ++nt) {
          long gn = bn + wc * 64 + nh * 32 + nt * 16 + col;
          float bv = bias[gn];
          long gm0 = bm + wr * 64 + mh * 32 + mt * 16 + quad * 4;
          f32x4 a = acc[mh * 2 + mt][nh * 2 + nt];
#pragma unroll
          for (int i = 0; i < 4; ++i)
            outf[(gm0 + i) * (long)D_ + gn] = a[i] + bv;
        }
#undef STAGE_PA
#undef STAGE_PB
}

// ---------------- host orchestration ----------------
extern "C" void kernel_launch(void* const* d_in, const int* in_sizes, int n_in,
                              void* d_out, int out_size, void* d_ws, size_t ws_size,
                              hipStream_t stream) {
  const float* x      = (const float*)d_in[0];
  const float* w_qkv  = (const float*)d_in[1];
  const float* b_qkv  = (const float*)d_in[2];
  const float* w_proj = (const float*)d_in[3];
  const float* b_proj = (const float*)d_in[4];
  float* out = (float*)d_out;

  bf16* xb     = (bf16*)d_ws;                       // [4096][1024]    8 MB (reused as attn)
  bf16* wqkvT  = xb + (size_t)S_ * D_;              // [3072][1024]    6 MB
  bf16* wprojT = wqkvT + (size_t)N3_ * D_;          // [1024][1024]    2 MB
  bf16* qkv    = wprojT + (size_t)D_ * D_;          // [4096][3072]   24 MB (V cols unused)
  bf16* vT     = qkv + (size_t)S_ * N3_;            // [1024][4096]    8 MB
  bf16* Opart  = vT + (size_t)D_ * S_;              // [2][4096][1024] 16 MB
  float* lws   = (float*)(Opart + (size_t)NSPLIT * S_ * D_);  // [2][16][4096] 0.5 MB
  bf16* attn   = xb;  // xb is dead after the QKV GEMM

  const float QSCALE = 0.125f * 1.44269504088896f;  // 1/sqrt(64) * log2(e)

  prep_kernel<<<dim3(8192), 256, 0, stream>>>(x, xb, w_qkv, wqkvT, w_proj, wprojT);
  gemm256_qkv<<<dim3(S_ / 256, N3_ / 256), 512, 0, stream>>>(
      xb, wqkvT, b_qkv, qkv, vT, QSCALE);
  // attn: 1024 blocks, 1-D grid, XCD-aware head grouping
  attn_kernel<<<dim3(1024), 256, 0, stream>>>(qkv, vT, Opart, lws);
  attn_combine<<<dim3((S_ * D_) / 2048), 256, 0, stream>>>(Opart, lws, attn);
  proj8_gemm<<<dim3(S_ / 128, D_ / 128), 256, 0, stream>>>(
      attn, wprojT, b_proj, out);
}